// Round 4
// baseline (600.072 us; speedup 1.0000x reference)
//
#include <hip/hip_runtime.h>
#include <math.h>

#define HDIM 4096
#define NEXP 64
#define NTOK 16384
#define MBLK 16            // tokens per block
#define KC   64            // k per chunk
#define NCHUNK (HDIM / KC) // 64
#define ASTR 68            // padded floats per token row in A_lds -> conflict-free
#define CSTRIDE 68

typedef float v4f __attribute__((ext_vector_type(4)));
typedef float v2f __attribute__((ext_vector_type(2)));

// DPP-add helper: x + dpp_select(x).
template <int CTRL, int RMASK>
__device__ __forceinline__ float dpp_add(float x) {
    int xi = __builtin_bit_cast(int, x);
    int yi = __builtin_amdgcn_update_dpp(0, xi, CTRL, RMASK, 0xF, true);
    return x + __builtin_bit_cast(float, yi);
}

// Fused router. 1024 blocks x 512 threads.
// R8 theory: R3 was LDS-BW-bound (512 ds_read_b128/CU/chunk x 12cyc = 6144cyc
// vs 2048cyc FMA -> 164us predicted, 184 measured). Fix: lane owns ALL 8 of
// its wave's experts (gate 100% in regs), 4 tokens -> 4 ds_read : 128 FMA per
// wave-chunk (LDS 768cyc < FMA 1024cyc per CU). MBLK 32->16 keeps acc at
// 4x8=32 VGPRs; gate double-buffer 64; total ~115 < 128 cap of (512,2).
// Two-phase loop swaps gA/gB by BINDING (no v_mov rotation).
__global__ __launch_bounds__(512, 2) void router_main(
    const float* __restrict__ hidden,
    const float* __restrict__ gate,
    float* __restrict__ out_rw,
    float* __restrict__ out_sel,
    float* __restrict__ psum_g,
    float* __restrict__ cnt_g,
    float* __restrict__ zsum_g)
{
    __shared__ float A_lds[2][MBLK * ASTR];   // 2 x 4.25 KB
    __shared__ float C_lds[MBLK * CSTRIDE];
    __shared__ float rden[MBLK];
    __shared__ unsigned hist[NEXP];

    const int t = threadIdx.x;
    const int lane = t & 63;
    const int wave = __builtin_amdgcn_readfirstlane(t >> 6);
    const int m0 = blockIdx.x * MBLK;
    const int ksub = lane & 15;   // k-slice owner: k = c*64 + ksub*4 .. +3
    const int tsub = lane >> 4;   // token sub-group 0..3 (tokens tsub*4..tsub*4+3)

    const v2f* __restrict__ A2 = (const v2f*)hidden;   // token row = 2048 v2f
    const v4f* __restrict__ G4 = (const v4f*)gate;     // expert row = 1024 v4f

    // staging: thread t stages token st = t>>5, v2f col sc = t&31 (8 B each,
    // all 512 threads -> 4 KB tile, balanced across waves)
    const int st = t >> 5;
    const int sc = t & 31;
    const size_t arow2 = (size_t)(m0 + st) * (HDIM / 2);

    float acc[4][8];
#pragma unroll
    for (int tt = 0; tt < 4; ++tt)
#pragma unroll
        for (int e = 0; e < 8; ++e) acc[tt][e] = 0.f;

    // prologue: stage chunk 0, prefetch A chunk 1, preload gate chunk 0
    v2f apref = __builtin_nontemporal_load(&A2[arow2 + sc]);
    *(v2f*)&A_lds[0][st * ASTR + sc * 2] = apref;
    apref = __builtin_nontemporal_load(&A2[arow2 + 32 + sc]);

    v4f gA[8], gB[8];
#pragma unroll
    for (int e = 0; e < 8; ++e)
        gA[e] = G4[(size_t)(8 * wave + e) * (HDIM / 4) + ksub];   // chunk 0
    __syncthreads();

    auto step = [&](int it, v4f (&gc)[8], v4f (&gn)[8]) {
        const int cur = it & 1;
        // prefetch next chunk's gate rows (consumed next step; clamped tail)
        const int cn = (it + 1 < NCHUNK) ? (it + 1) : (NCHUNK - 1);
#pragma unroll
        for (int e = 0; e < 8; ++e)
            gn[e] = G4[(size_t)(8 * wave + e) * (HDIM / 4) + cn * 16 + ksub];
        // stage next chunk's A tile into the other buffer
        if (it + 1 < NCHUNK)
            *(v2f*)&A_lds[cur ^ 1][st * ASTR + sc * 2] = apref;
        // prefetch A for chunk it+2 (clamped tail)
        const int ca = (it + 2 < NCHUNK) ? (it + 2) : (NCHUNK - 1);
        apref = __builtin_nontemporal_load(&A2[arow2 + ca * 32 + sc]);
        // compute: 4 tokens x (1 ds_read_b128 -> 32 FMAs)
        const float* Ab = &A_lds[cur][ksub * 4];
#pragma unroll
        for (int tt = 0; tt < 4; ++tt) {
            v4f a = *(const v4f*)&Ab[(tsub * 4 + tt) * ASTR];
#pragma unroll
            for (int e = 0; e < 8; ++e) {
                acc[tt][e] = fmaf(a.x, gc[e].x, acc[tt][e]);
                acc[tt][e] = fmaf(a.y, gc[e].y, acc[tt][e]);
                acc[tt][e] = fmaf(a.z, gc[e].z, acc[tt][e]);
                acc[tt][e] = fmaf(a.w, gc[e].w, acc[tt][e]);
            }
        }
        __syncthreads();
    };

    for (int it = 0; it < NCHUNK; it += 2) {
        step(it,     gA, gB);
        step(it + 1, gB, gA);
    }

    // k-reduction over ksub (lane bits 0..3): xor1, xor2, 8-mirror, 16-mirror
#pragma unroll
    for (int tt = 0; tt < 4; ++tt)
#pragma unroll
        for (int e = 0; e < 8; ++e) {
            float x = acc[tt][e];
            x = dpp_add<0xB1,  0xF>(x);   // quad_perm xor1
            x = dpp_add<0x4E,  0xF>(x);   // quad_perm xor2
            x = dpp_add<0x141, 0xF>(x);   // row_half_mirror
            x = dpp_add<0x140, 0xF>(x);   // row_mirror
            acc[tt][e] = x;
        }
    if (ksub == 0) {
#pragma unroll
        for (int tt = 0; tt < 4; ++tt) {
            const int tok = tsub * 4 + tt;
            *(float4*)&C_lds[tok * CSTRIDE + wave * 8 + 0] =
                make_float4(acc[tt][0], acc[tt][1], acc[tt][2], acc[tt][3]);
            *(float4*)&C_lds[tok * CSTRIDE + wave * 8 + 4] =
                make_float4(acc[tt][4], acc[tt][5], acc[tt][6], acc[tt][7]);
        }
    }

    if (t < NEXP) hist[t] = 0u;
    __syncthreads();

    if (wave != 0) return;   // epilogue on wave 0 (lanes 0..15 = tokens)

    float z = 0.f;
    if (lane < MBLK) {
        // top-2 (strict >, ascending e => ties pick lower index, matches jax)
        float v1 = -INFINITY, v2 = -INFINITY;
        int i1 = 0, i2 = 0;
        for (int e = 0; e < NEXP; ++e) {
            float v = C_lds[lane * CSTRIDE + e];
            if (v > v1)      { v2 = v1; i2 = i1; v1 = v; i1 = e; }
            else if (v > v2) { v2 = v;  i2 = e; }
        }
        atomicAdd(&hist[i1], 1u);
        atomicAdd(&hist[i2], 1u);

        float d = 0.f;
        for (int e = 0; e < NEXP; ++e) {
            float ev = expf(C_lds[lane * CSTRIDE + e] - v1);
            C_lds[lane * CSTRIDE + e] = ev;
            d += ev;
        }
        rden[lane] = 1.0f / d;
        float lse = v1 + logf(d);
        z = lse * lse;

        float e2 = expf(v2 - v1);
        float w2 = e2 / (1.f + e2);
        float w1 = 1.f - w2;
        int tok = m0 + lane;
        out_rw[2 * tok + 0] = w1;
        out_rw[2 * tok + 1] = w2;
        out_sel[2 * tok + 0] = (float)i1;
        out_sel[2 * tok + 1] = (float)i2;
    }

#pragma unroll
    for (int off = 32; off > 0; off >>= 1) z += __shfl_down(z, off);
    if (lane == 0) atomicAdd(zsum_g, z);

    // per-expert prob sums over this block's 16 tokens (lane = expert)
    float ps = 0.f;
    for (int m = 0; m < MBLK; ++m)
        ps += C_lds[m * CSTRIDE + lane] * rden[m];
    atomicAdd(&psum_g[lane], ps);
    atomicAdd(&cnt_g[lane], (float)hist[lane]);
}

__global__ void router_final(const float* __restrict__ ws, float* __restrict__ out_loss)
{
    int e = threadIdx.x;  // 64 threads
    const float inv = 1.0f / (float)NTOK;
    float p = (ws[64 + e] * inv) * (ws[e] * inv);
#pragma unroll
    for (int off = 32; off > 0; off >>= 1) p += __shfl_down(p, off);
    if (e == 0)
        out_loss[0] = 0.01f * (64.f * p) + 0.001f * (ws[128] * inv);
}

extern "C" void kernel_launch(void* const* d_in, const int* in_sizes, int n_in,
                              void* d_out, int out_size, void* d_ws, size_t ws_size,
                              hipStream_t stream) {
    const float* hidden = (const float*)d_in[0];   // [4,4096,4096] fp32
    const float* gate   = (const float*)d_in[1];   // [64,4096] fp32
    float* out = (float*)d_out;                    // 65537 floats
    float* ws  = (float*)d_ws;                     // psum[64] | cnt[64] | zsum[1]

    hipMemsetAsync(d_ws, 0, 129 * sizeof(float), stream);
    router_main<<<dim3(NTOK / MBLK), dim3(512), 0, stream>>>(
        hidden, gate,
        out,                 // routing weights
        out + NTOK * 2,      // selected experts (as floats)
        ws, ws + 64, ws + 128);
    router_final<<<dim3(1), dim3(64), 0, stream>>>(ws, out + NTOK * 4);
}

// Round 5
// 448.225 us; speedup vs baseline: 1.3388x; 1.3388x over previous
//
#include <hip/hip_runtime.h>
#include <math.h>

#define HDIM 4096
#define NEXP 64
#define NTOK 16384
#define MBLK 32            // tokens per block (all amortize one gate pass)
#define KC   64            // k per chunk
#define NCHUNK (HDIM / KC) // 64
#define ASTR 68            // padded floats per token row in A_lds -> conflict-free
#define CSTRIDE 68

typedef float v4f __attribute__((ext_vector_type(4)));

// DPP-add helper: x + dpp_select(x).
template <int CTRL, int RMASK>
__device__ __forceinline__ float dpp_add(float x) {
    int xi = __builtin_bit_cast(int, x);
    int yi = __builtin_amdgcn_update_dpp(0, xi, CTRL, RMASK, 0xF, true);
    return x + __builtin_bit_cast(float, yi);
}

// Barrier WITHOUT the vmcnt(0) drain __syncthreads() emits. Only LDS ops
// (ds_write of the next A-buffer) must be visible across it; in-flight
// global loads land in REGISTERS and the compiler inserts counted vmcnt
// waits before their first use. This keeps the A (HBM) and gate (L2)
// prefetches in flight across chunk boundaries (T4: never drain vmcnt
// in the main loop).
__device__ __forceinline__ void barrier_lgkm_only() {
    asm volatile("s_waitcnt lgkmcnt(0)\n\ts_barrier" ::: "memory");
}

// Fused router. 512 blocks x 512 threads.
// R9 = R3 structure (184us, conflict-free broadcast reads) + lgkmcnt-only
// barrier. R4's lane relayout (4-way read conflicts, 8.5M conflict cycles)
// is reverted. R3's residual stall theory: per-chunk __syncthreads drained
// vmcnt(0), exposing ~900cy HBM A-prefetch latency serially every chunk.
// lane = e_sub*16 + k_sub. Wave w owns experts {8w+e_sub, 8w+4+e_sub};
// acc[MBLK][2] = 64 VGPRs. Gate reg-double-buffered one chunk ahead.
// VGPR ~108: fits the (512,2)=128 cap, no spill (R3-verified).
__global__ __launch_bounds__(512, 2) void router_main(
    const float* __restrict__ hidden,
    const float* __restrict__ gate,
    float* __restrict__ out_rw,
    float* __restrict__ out_sel,
    float* __restrict__ psum_g,
    float* __restrict__ cnt_g,
    float* __restrict__ zsum_g)
{
    __shared__ float A_lds[2][MBLK * ASTR];   // 2 x 8.5 KB
    __shared__ float C_lds[MBLK * CSTRIDE];
    __shared__ float rden[MBLK];
    __shared__ unsigned hist[NEXP];

    const int t = threadIdx.x;
    const int lane = t & 63;
    const int wave = __builtin_amdgcn_readfirstlane(t >> 6);
    const int m0 = blockIdx.x * MBLK;
    const int ksub = lane & 15;   // k-slice owner: k = c*64 + ksub*4 .. +3
    const int esub = lane >> 4;   // expert sub-index 0..3

    const v4f* __restrict__ A4 = (const v4f*)hidden;   // token row = 1024 f4
    const v4f* __restrict__ G4 = (const v4f*)gate;     // expert row = 1024 f4

    // staging assignment: thread t stages token st = t>>4, f4-col sc = t&15
    const int st = t >> 4;
    const int sc = t & 15;
    const size_t arow = (size_t)(m0 + st) * (HDIM / 4);

    // gate rows for this lane's two expert groups
    const size_t grow0 = (size_t)(8 * wave + esub) * (HDIM / 4);
    const size_t grow1 = (size_t)(8 * wave + 4 + esub) * (HDIM / 4);

    float acc[MBLK][2];
#pragma unroll
    for (int tt = 0; tt < MBLK; ++tt) { acc[tt][0] = 0.f; acc[tt][1] = 0.f; }

    // prologue: stage chunk 0, prefetch A chunk 1, preload gate chunk 0
    v4f apref = __builtin_nontemporal_load(&A4[arow + sc]);
    *(v4f*)&A_lds[0][st * ASTR + sc * 4] = apref;
    apref = __builtin_nontemporal_load(&A4[arow + 16 + sc]);
    v4f gc0 = G4[grow0 + ksub];
    v4f gc1 = G4[grow1 + ksub];
    __syncthreads();

    for (int it = 0; it < NCHUNK; ++it) {
        const int cur = it & 1;
        // prefetch next chunk's gate fragments (consumed next iteration)
        const int cn = (it + 1 < NCHUNK) ? (it + 1) : (NCHUNK - 1);
        v4f gn0 = G4[grow0 + cn * 16 + ksub];
        v4f gn1 = G4[grow1 + cn * 16 + ksub];
        // stage next chunk's A tile into the other buffer
        if (it + 1 < NCHUNK)
            *(v4f*)&A_lds[cur ^ 1][st * ASTR + sc * 4] = apref;
        // prefetch A for chunk it+2
        const int ca = (it + 2 < NCHUNK) ? (it + 2) : (NCHUNK - 1);
        apref = __builtin_nontemporal_load(&A4[arow + ca * 16 + sc]);
        // compute: 32 tokens x (1 ds_read_b128 broadcast -> 8 FMAs)
        const float* Ab = &A_lds[cur][ksub * 4];
#pragma unroll
        for (int tt = 0; tt < MBLK; ++tt) {
            v4f a = *(const v4f*)&Ab[tt * ASTR];
            acc[tt][0] = fmaf(a.x, gc0.x, acc[tt][0]);
            acc[tt][0] = fmaf(a.y, gc0.y, acc[tt][0]);
            acc[tt][0] = fmaf(a.z, gc0.z, acc[tt][0]);
            acc[tt][0] = fmaf(a.w, gc0.w, acc[tt][0]);
            acc[tt][1] = fmaf(a.x, gc1.x, acc[tt][1]);
            acc[tt][1] = fmaf(a.y, gc1.y, acc[tt][1]);
            acc[tt][1] = fmaf(a.z, gc1.z, acc[tt][1]);
            acc[tt][1] = fmaf(a.w, gc1.w, acc[tt][1]);
        }
        barrier_lgkm_only();
        gc0 = gn0;
        gc1 = gn1;
    }

    // k-reduction: butterfly over k_sub (lane bits 0..3): xor1, xor2, xor4, xor8
#pragma unroll
    for (int tt = 0; tt < MBLK; ++tt)
#pragma unroll
        for (int eg = 0; eg < 2; ++eg) {
            float x = acc[tt][eg];
            x = dpp_add<0xB1,  0xF>(x);   // quad_perm xor1
            x = dpp_add<0x4E,  0xF>(x);   // quad_perm xor2
            x = dpp_add<0x141, 0xF>(x);   // row_half_mirror (xor4 after quad-sums)
            x = dpp_add<0x140, 0xF>(x);   // row_mirror (xor8 after 8-sums)
            acc[tt][eg] = x;
        }
    if (ksub == 0) {
#pragma unroll
        for (int tt = 0; tt < MBLK; ++tt) {
            C_lds[tt * CSTRIDE + wave * 8 + esub]     = acc[tt][0];
            C_lds[tt * CSTRIDE + wave * 8 + 4 + esub] = acc[tt][1];
        }
    }

    if (t < NEXP) hist[t] = 0u;
    __syncthreads();

    if (wave != 0) return;   // epilogue on wave 0 (lanes 0..31 = tokens)

    float z = 0.f;
    if (lane < MBLK) {
        // top-2 (strict >, ascending e => ties pick lower index, matches jax)
        float v1 = -INFINITY, v2 = -INFINITY;
        int i1 = 0, i2 = 0;
        for (int e = 0; e < NEXP; ++e) {
            float v = C_lds[lane * CSTRIDE + e];
            if (v > v1)      { v2 = v1; i2 = i1; v1 = v; i1 = e; }
            else if (v > v2) { v2 = v;  i2 = e; }
        }
        atomicAdd(&hist[i1], 1u);
        atomicAdd(&hist[i2], 1u);

        float d = 0.f;
        for (int e = 0; e < NEXP; ++e) {
            float ev = expf(C_lds[lane * CSTRIDE + e] - v1);
            C_lds[lane * CSTRIDE + e] = ev;
            d += ev;
        }
        rden[lane] = 1.0f / d;
        float lse = v1 + logf(d);
        z = lse * lse;

        float e2 = expf(v2 - v1);
        float w2 = e2 / (1.f + e2);
        float w1 = 1.f - w2;
        int tok = m0 + lane;
        out_rw[2 * tok + 0] = w1;
        out_rw[2 * tok + 1] = w2;
        out_sel[2 * tok + 0] = (float)i1;
        out_sel[2 * tok + 1] = (float)i2;
    }

#pragma unroll
    for (int off = 32; off > 0; off >>= 1) z += __shfl_down(z, off);
    if (lane == 0) atomicAdd(zsum_g, z);

    // per-expert prob sums over this block's 32 tokens (lane = expert)
    float ps = 0.f;
    for (int m = 0; m < MBLK; ++m)
        ps += C_lds[m * CSTRIDE + lane] * rden[m];
    atomicAdd(&psum_g[lane], ps);
    atomicAdd(&cnt_g[lane], (float)hist[lane]);
}

__global__ void router_final(const float* __restrict__ ws, float* __restrict__ out_loss)
{
    int e = threadIdx.x;  // 64 threads
    const float inv = 1.0f / (float)NTOK;
    float p = (ws[64 + e] * inv) * (ws[e] * inv);
#pragma unroll
    for (int off = 32; off > 0; off >>= 1) p += __shfl_down(p, off);
    if (e == 0)
        out_loss[0] = 0.01f * (64.f * p) + 0.001f * (ws[128] * inv);
}

extern "C" void kernel_launch(void* const* d_in, const int* in_sizes, int n_in,
                              void* d_out, int out_size, void* d_ws, size_t ws_size,
                              hipStream_t stream) {
    const float* hidden = (const float*)d_in[0];   // [4,4096,4096] fp32
    const float* gate   = (const float*)d_in[1];   // [64,4096] fp32
    float* out = (float*)d_out;                    // 65537 floats
    float* ws  = (float*)d_ws;                     // psum[64] | cnt[64] | zsum[1]

    hipMemsetAsync(d_ws, 0, 129 * sizeof(float), stream);
    router_main<<<dim3(NTOK / MBLK), dim3(512), 0, stream>>>(
        hidden, gate,
        out,                 // routing weights
        out + NTOK * 2,      // selected experts (as floats)
        ws, ws + 64, ws + 128);
    router_final<<<dim3(1), dim3(64), 0, stream>>>(ws, out + NTOK * 4);
}

// Round 6
// 429.907 us; speedup vs baseline: 1.3958x; 1.0426x over previous
//
#include <hip/hip_runtime.h>
#include <math.h>

#define HDIM 4096
#define NEXP 64
#define NTOK 16384
#define MBLK 64            // tokens per block
#define KC   64            // k per chunk
#define NCHUNK (HDIM / KC) // 64
#define CSTRIDE 68

typedef float v4f __attribute__((ext_vector_type(4)));
typedef short bh4 __attribute__((ext_vector_type(4)));     // 4 x bf16 (MFMA operand)
typedef float f32x16 __attribute__((ext_vector_type(16))); // MFMA accumulator

#if defined(__has_builtin)
#if __has_builtin(__builtin_amdgcn_mfma_f32_32x32x8bf16_1k)
#define HAVE_MFMA_BUILTIN 1
#endif
#endif

__device__ __forceinline__ f32x16 mfma_bf16(bh4 a, bh4 b, f32x16 c) {
#ifdef HAVE_MFMA_BUILTIN
    return __builtin_amdgcn_mfma_f32_32x32x8bf16_1k(a, b, c, 0, 0, 0);
#else
    asm("v_mfma_f32_32x32x8_bf16 %0, %1, %2, %0" : "+v"(c) : "v"(a), "v"(b));
    return c;
#endif
}

// Barrier WITHOUT the vmcnt(0) drain __syncthreads() emits (R5: +20us win).
// LDS ops must be visible across it (lgkmcnt); in-flight global prefetches
// land in registers and keep flying across chunk boundaries.
__device__ __forceinline__ void barrier_lgkm_only() {
    asm volatile("s_waitcnt lgkmcnt(0)\n\ts_barrier" ::: "memory");
}

// 3-way bf16 split (RNE, RNE, trunc): a ~= a0 + a1 + a2 to ~24 significand
// bits. With 6 MFMA products (i+j<=2) the logit error ~2e-7 — below the
// fp32-reorder error of the passing VALU baseline, so top-2 flips are LESS
// likely than baseline.
__device__ __forceinline__ void split3(float v, unsigned short& h0,
                                       unsigned short& h1, unsigned short& h2) {
    unsigned b0 = __builtin_bit_cast(unsigned, v);
    unsigned r0 = (b0 + 0x7FFFu + ((b0 >> 16) & 1u)) & 0xFFFF0000u;
    h0 = (unsigned short)(r0 >> 16);
    float v1 = v - __builtin_bit_cast(float, r0);      // exact (Sterbenz)
    unsigned b1 = __builtin_bit_cast(unsigned, v1);
    unsigned r1 = (b1 + 0x7FFFu + ((b1 >> 16) & 1u)) & 0xFFFF0000u;
    h1 = (unsigned short)(r1 >> 16);
    float v2 = v1 - __builtin_bit_cast(float, r1);     // exact
    h2 = (unsigned short)(__builtin_bit_cast(unsigned, v2) >> 16);
}

// R6 structure: MFMA router. 256 blocks x 512 threads (8 waves, 1 block/CU).
// R5 post-mortem: VALU path was LDS-port-bound (512 ds_read_b128/CU/chunk
// x 12cyc = 6144cyc = measured 6150cyc/chunk) with a 54.6us FMA-issue floor.
// MFMA path: 64-token x 64-expert block; wave (c=w&3, h=w>>2): output tile
// c (mtp=c&1: 32 tokens, ntp=c>>1: 32 experts), K-half h (ks 4h..4h+3 of 8).
// v_mfma_f32_32x32x8_bf16, classic layouts: A row=l&31 k=(l>>5)*4+j;
// D col=l&31 row=(r&3)+8*(r>>2)+4*(l>>5)  [m74-verified on gfx950].
// A (HBM, nt) and gate (L2) staged per chunk into frag-major LDS with
// slot = lane ^ (ks<<3) XOR swizzle -> both staging writes and frag reads
// are full-bandwidth (every bank 4 dwords, zero conflict).
// Per CU per chunk: HBM 1638cyc (the floor) > LDS ~1300 > VALU ~900 > MFMA ~400.
__global__ __launch_bounds__(512, 1) void router_main(
    const float* __restrict__ hidden,
    const float* __restrict__ gate,
    float* __restrict__ out_rw,
    float* __restrict__ out_sel,
    float* __restrict__ psum_g,
    float* __restrict__ cnt_g,
    float* __restrict__ zsum_g)
{
    // [dbuf][A=0/B=1][plane][half: mtp|ntp][ks8][slot]  (8 B each) = 96 KB
    __shared__ uint2 frag[2][2][3][2][8][64];
    __shared__ float Pacc[4][16][64];          // cross-wave partial acc, 16 KB
    __shared__ float C_lds[MBLK * CSTRIDE];
    __shared__ float rden[MBLK];
    __shared__ unsigned hist[NEXP];

    const int t = threadIdx.x;
    const int lane = t & 63;
    const int wave = __builtin_amdgcn_readfirstlane(t >> 6);
    const int m0 = blockIdx.x * MBLK;
    const int c = wave & 3, h = wave >> 2;
    const int mtp = c & 1, ntp = c >> 1;

    const v4f* __restrict__ A4 = (const v4f*)hidden;   // token row = 1024 f4
    const v4f* __restrict__ G4 = (const v4f*)gate;     // expert row = 1024 f4

    // staging: thread t handles row sr (token AND expert sr) and ks-step sk:
    // 8 consecutive fp32 (= one full ks8 step) per array per chunk.
    const int sr = t >> 3;
    const int sk = t & 7;
    const size_t abase = (size_t)(m0 + sr) * (HDIM / 4) + sk * 2;
    const size_t gbase = (size_t)sr * (HDIM / 4) + sk * 2;

    // split + pack + swizzled frag-major store (conflict-free by XOR slot)
    auto stage = [&](int buf, int ab, v4f x0, v4f x1) {
        float av[8] = {x0.x, x0.y, x0.z, x0.w, x1.x, x1.y, x1.z, x1.w};
        unsigned short hs[3][8];
#pragma unroll
        for (int u = 0; u < 8; ++u) split3(av[u], hs[0][u], hs[1][u], hs[2][u]);
        const int half = sr >> 5, rl = sr & 31;
#pragma unroll
        for (int p = 0; p < 3; ++p) {
            frag[buf][ab][p][half][sk][rl ^ (sk << 3)] =
                make_uint2((unsigned)hs[p][0] | ((unsigned)hs[p][1] << 16),
                           (unsigned)hs[p][2] | ((unsigned)hs[p][3] << 16));
            frag[buf][ab][p][half][sk][(32 + rl) ^ (sk << 3)] =
                make_uint2((unsigned)hs[p][4] | ((unsigned)hs[p][5] << 16),
                           (unsigned)hs[p][6] | ((unsigned)hs[p][7] << 16));
        }
    };

    // prologue: stage chunk 0, prefetch chunk 1
    v4f pa0 = __builtin_nontemporal_load(&A4[abase]);
    v4f pa1 = __builtin_nontemporal_load(&A4[abase + 1]);
    v4f pg0 = G4[gbase];
    v4f pg1 = G4[gbase + 1];
    stage(0, 0, pa0, pa1);
    stage(0, 1, pg0, pg1);
    pa0 = __builtin_nontemporal_load(&A4[abase + 16]);
    pa1 = __builtin_nontemporal_load(&A4[abase + 17]);
    pg0 = G4[gbase + 16];
    pg1 = G4[gbase + 17];
    __syncthreads();

    f32x16 acc{};

    for (int it = 0; it < NCHUNK; ++it) {
        const int cur = it & 1;
        if (it + 1 < NCHUNK) {               // convert+write chunk it+1
            stage(cur ^ 1, 0, pa0, pa1);
            stage(cur ^ 1, 1, pg0, pg1);
        }
        if (it + 2 < NCHUNK) {               // issue global loads for it+2
            const size_t off = (size_t)(it + 2) * 16;
            pa0 = __builtin_nontemporal_load(&A4[abase + off]);
            pa1 = __builtin_nontemporal_load(&A4[abase + off + 1]);
            pg0 = G4[gbase + off];
            pg1 = G4[gbase + off + 1];
        }
        // compute: 4 ks8-steps, 6 frag reads + 6 MFMA each
#pragma unroll
        for (int s = 0; s < 4; ++s) {
            const int k8 = h * 4 + s;
            const int slot = lane ^ (k8 << 3);
            bh4 a0 = __builtin_bit_cast(bh4, frag[cur][0][0][mtp][k8][slot]);
            bh4 a1 = __builtin_bit_cast(bh4, frag[cur][0][1][mtp][k8][slot]);
            bh4 a2 = __builtin_bit_cast(bh4, frag[cur][0][2][mtp][k8][slot]);
            bh4 b0 = __builtin_bit_cast(bh4, frag[cur][1][0][ntp][k8][slot]);
            bh4 b1 = __builtin_bit_cast(bh4, frag[cur][1][1][ntp][k8][slot]);
            bh4 b2 = __builtin_bit_cast(bh4, frag[cur][1][2][ntp][k8][slot]);
            acc = mfma_bf16(a0, b0, acc);
            acc = mfma_bf16(a1, b0, acc);
            acc = mfma_bf16(a0, b1, acc);
            acc = mfma_bf16(a1, b1, acc);
            acc = mfma_bf16(a2, b0, acc);
            acc = mfma_bf16(a0, b2, acc);
        }
        barrier_lgkm_only();
    }

    // MFMA result -> VALU/LDS read guard
    asm volatile("s_nop 7\n\ts_nop 7\n\ts_nop 7" :::);

    if (h == 1) {
#pragma unroll
        for (int r = 0; r < 16; ++r) Pacc[c][r][lane] = acc[r];
    }
    if (t < NEXP) hist[t] = 0u;
    __syncthreads();
    if (h == 0) {
#pragma unroll
        for (int r = 0; r < 16; ++r) {
            float x = acc[r] + Pacc[c][r][lane];
            const int tok = mtp * 32 + (r & 3) + 8 * (r >> 2) + 4 * (lane >> 5);
            const int e = ntp * 32 + (lane & 31);
            C_lds[tok * CSTRIDE + e] = x;
        }
    }
    __syncthreads();

    if (wave != 0) return;   // epilogue on wave 0 (lanes 0..63 = tokens)

    float z = 0.f;
    {
        // top-2 (strict >, ascending e => ties pick lower index, matches jax)
        float v1 = -INFINITY, v2 = -INFINITY;
        int i1 = 0, i2 = 0;
        for (int e = 0; e < NEXP; ++e) {
            float v = C_lds[lane * CSTRIDE + e];
            if (v > v1)      { v2 = v1; i2 = i1; v1 = v; i1 = e; }
            else if (v > v2) { v2 = v;  i2 = e; }
        }
        atomicAdd(&hist[i1], 1u);
        atomicAdd(&hist[i2], 1u);

        float d = 0.f;
        for (int e = 0; e < NEXP; ++e) {
            float ev = expf(C_lds[lane * CSTRIDE + e] - v1);
            C_lds[lane * CSTRIDE + e] = ev;
            d += ev;
        }
        rden[lane] = 1.0f / d;
        float lse = v1 + logf(d);
        z = lse * lse;

        float e2 = expf(v2 - v1);
        float w2 = e2 / (1.f + e2);
        float w1 = 1.f - w2;
        int tok = m0 + lane;
        out_rw[2 * tok + 0] = w1;
        out_rw[2 * tok + 1] = w2;
        out_sel[2 * tok + 0] = (float)i1;
        out_sel[2 * tok + 1] = (float)i2;
    }

#pragma unroll
    for (int off = 32; off > 0; off >>= 1) z += __shfl_down(z, off);
    if (lane == 0) atomicAdd(zsum_g, z);

    // per-expert prob sums over this block's 64 tokens (lane = expert)
    float ps = 0.f;
    for (int m = 0; m < MBLK; ++m)
        ps += C_lds[m * CSTRIDE + lane] * rden[m];
    atomicAdd(&psum_g[lane], ps);
    atomicAdd(&cnt_g[lane], (float)hist[lane]);
}

__global__ void router_final(const float* __restrict__ ws, float* __restrict__ out_loss)
{
    int e = threadIdx.x;  // 64 threads
    const float inv = 1.0f / (float)NTOK;
    float p = (ws[64 + e] * inv) * (ws[e] * inv);
#pragma unroll
    for (int off = 32; off > 0; off >>= 1) p += __shfl_down(p, off);
    if (e == 0)
        out_loss[0] = 0.01f * (64.f * p) + 0.001f * (ws[128] * inv);
}

extern "C" void kernel_launch(void* const* d_in, const int* in_sizes, int n_in,
                              void* d_out, int out_size, void* d_ws, size_t ws_size,
                              hipStream_t stream) {
    const float* hidden = (const float*)d_in[0];   // [4,4096,4096] fp32
    const float* gate   = (const float*)d_in[1];   // [64,4096] fp32
    float* out = (float*)d_out;                    // 65537 floats
    float* ws  = (float*)d_ws;                     // psum[64] | cnt[64] | zsum[1]

    hipMemsetAsync(d_ws, 0, 129 * sizeof(float), stream);
    router_main<<<dim3(NTOK / MBLK), dim3(512), 0, stream>>>(
        hidden, gate,
        out,                 // routing weights
        out + NTOK * 2,      // selected experts (as floats)
        ws, ws + 64, ws + 128);
    router_final<<<dim3(1), dim3(64), 0, stream>>>(ws, out + NTOK * 4);
}

// Round 7
// 402.158 us; speedup vs baseline: 1.4921x; 1.0690x over previous
//
#include <hip/hip_runtime.h>
#include <math.h>

#define HDIM 4096
#define NEXP 64
#define NTOK 16384
#define MBLK 32            // tokens per block
#define NCHUNK 64          // 64 k per chunk, 64 chunks
#define CSTRIDE 68
#define GS_FLOATS 262144   // 1 MB pre-split gate in workspace (ws evidence: ~1 GB fills)

typedef float v4f __attribute__((ext_vector_type(4)));
typedef short bh4 __attribute__((ext_vector_type(4)));     // 4 x bf16 (MFMA operand)
typedef float f32x16 __attribute__((ext_vector_type(16))); // MFMA accumulator

#if defined(__has_builtin)
#if __has_builtin(__builtin_amdgcn_mfma_f32_32x32x8bf16_1k)
#define HAVE_MFMA_BUILTIN 1
#endif
#endif

__device__ __forceinline__ f32x16 mfma_bf16(bh4 a, bh4 b, f32x16 c) {
#ifdef HAVE_MFMA_BUILTIN
    return __builtin_amdgcn_mfma_f32_32x32x8bf16_1k(a, b, c, 0, 0, 0);
#else
    asm("v_mfma_f32_32x32x8_bf16 %0, %1, %2, %0" : "+v"(c) : "v"(a), "v"(b));
    return c;
#endif
}

// Barrier WITHOUT the vmcnt(0) drain __syncthreads() emits (R5: +20us win).
__device__ __forceinline__ void barrier_lgkm_only() {
    asm volatile("s_waitcnt lgkmcnt(0)\n\ts_barrier" ::: "memory");
}

// 2-way bf16 split (RNE both): v = h0 + h1 + eps, |eps| <= 2^-18|v|.
// With all 4 cross products in MFMA, logit error ~1e-6 = fp32-accum noise,
// i.e. the same top-2 flip risk as the R6 kernel that passed.
__device__ __forceinline__ void split2(float v, unsigned short& h0,
                                       unsigned short& h1) {
    unsigned b0 = __builtin_bit_cast(unsigned, v);
    unsigned r0 = (b0 + 0x7FFFu + ((b0 >> 16) & 1u)) & 0xFFFF0000u;
    h0 = (unsigned short)(r0 >> 16);
    float v1 = v - __builtin_bit_cast(float, r0);      // exact
    unsigned b1 = __builtin_bit_cast(unsigned, v1);
    h1 = (unsigned short)((b1 + 0x7FFFu + ((b1 >> 16) & 1u)) >> 16);  // RNE
}

__device__ __forceinline__ uint2 pack4(const unsigned short* h) {
    return make_uint2((unsigned)h[0] | ((unsigned)h[1] << 16),
                      (unsigned)h[2] | ((unsigned)h[3] << 16));
}

// Pre-kernel: split gate [64][4096] fp32 into 2 bf16 planes stored in MFMA
// B-fragment order: gs[((k8g*2 + plane)*2 + ntp)*64 + lane] (uint2 = bh4).
// Lane l's fragment for k8-step k8g: expert = ntp*32 + (l&31),
// k = k8g*8 + (l>>5)*4 + j  [R6-verified 32x32x8 B layout].
// Runs once per launch; all 512 main blocks then read B coalesced from L2
// with ZERO split work (R6 re-split the same 1 MB gate 256 x 64 times).
__global__ __launch_bounds__(256) void gate_presplit(
    const float* __restrict__ gate, uint2* __restrict__ gs)
{
    const int f = blockIdx.x * 256 + threadIdx.x;   // 65536 = 512 k8g x 2 ntp x 64 lane
    const int l = f & 63;
    const int ntp = (f >> 6) & 1;
    const int k8g = f >> 7;
    const int e = ntp * 32 + (l & 31);
    const int k = k8g * 8 + (l >> 5) * 4;
    v4f x = *(const v4f*)&gate[(size_t)e * HDIM + k];
    float xv[4] = {x.x, x.y, x.z, x.w};
    unsigned short lo[4], hi[4];
#pragma unroll
    for (int j = 0; j < 4; ++j) split2(xv[j], lo[j], hi[j]);
    gs[((size_t)(k8g * 2 + 0) * 2 + ntp) * 64 + l] = pack4(lo);
    gs[((size_t)(k8g * 2 + 1) * 2 + ntp) * 64 + l] = pack4(hi);
}

// R7 main: 512 blocks x 256 threads (4 waves), 2 independent blocks/CU.
// R6 post-mortem: ~157us; staging (split3 VALU + 288 DS instrs/CU/chunk) in
// a 1-block lockstep barrier serialized everything. R7: gate fully removed
// from the block (pre-split, B straight L2->regs, reg-double-buffered one
// chunk ahead); A-only LDS staging (16 KB dbuf); 2-way split, 4 products.
// Waves: ntp = w&1 (expert half), h = w>>1 (K half: k8 in {4h..4h+3}).
// A-frag LDS XOR swizzle: slot = l ^ ((k8&1)<<3) -> writes and reads both
// hit each bank-pair exactly 4x (the b64 minimum). HBM A (16 KB/CU/chunk,
// 1600cyc) is the binding pipe -> ~43us roofline.
__global__ __launch_bounds__(256, 4) void router_main(
    const float* __restrict__ hidden,
    const uint2* __restrict__ gs,
    float* __restrict__ out_rw,
    float* __restrict__ out_sel,
    float* __restrict__ psum_g,
    float* __restrict__ cnt_g,
    float* __restrict__ zsum_g)
{
    __shared__ uint2 Af[2][8][2][64];   // [dbuf][k8][plane][slot] = 16 KB
    __shared__ float Pacc[2][16][64];   // cross-wave K-half reduction, 8 KB
    __shared__ float C_lds[MBLK * CSTRIDE];
    __shared__ float rden[MBLK];
    __shared__ unsigned hist[NEXP];

    const int t = threadIdx.x;
    const int lane = t & 63;
    const int wave = __builtin_amdgcn_readfirstlane(t >> 6);
    const int ntp = wave & 1, h = wave >> 1;
    const int m0 = blockIdx.x * MBLK;

    const v4f* __restrict__ A4 = (const v4f*)hidden;   // token row = 1024 f4

    // staging: thread t owns token row = t>>3, k8-step k8s = t&7
    // (8 consecutive fp32 per chunk = one bh4-pair fragment, coalesced read)
    const int row = t >> 3;
    const int k8s = t & 7;
    const size_t abase = (size_t)(m0 + row) * (HDIM / 4) + k8s * 2;
    const int sw_w = (k8s & 1) << 3;

    auto stageA = [&](int buf, v4f x0, v4f x1) {
        float av[8] = {x0.x, x0.y, x0.z, x0.w, x1.x, x1.y, x1.z, x1.w};
        unsigned short lo[8], hi[8];
#pragma unroll
        for (int u = 0; u < 8; ++u) split2(av[u], lo[u], hi[u]);
        const int s0 = row ^ sw_w;        // kgrp 0 slot
        Af[buf][k8s][0][s0]      = pack4(lo);
        Af[buf][k8s][0][s0 + 32] = pack4(lo + 4);
        Af[buf][k8s][1][s0]      = pack4(hi);
        Af[buf][k8s][1][s0 + 32] = pack4(hi + 4);
    };

    f32x16 acc{};

    // prologue: stage chunk 0, prefetch A chunk 1, preload B chunk 0
    v4f ap0 = __builtin_nontemporal_load(&A4[abase]);
    v4f ap1 = __builtin_nontemporal_load(&A4[abase + 1]);
    stageA(0, ap0, ap1);
    ap0 = __builtin_nontemporal_load(&A4[abase + 16]);
    ap1 = __builtin_nontemporal_load(&A4[abase + 17]);

    uint2 bA[8], bB[8];
#pragma unroll
    for (int s = 0; s < 4; ++s) {
        const int k8g = h * 4 + s;
        bA[2 * s + 0] = gs[((size_t)(k8g * 2 + 0) * 2 + ntp) * 64 + lane];
        bA[2 * s + 1] = gs[((size_t)(k8g * 2 + 1) * 2 + ntp) * 64 + lane];
    }
    __syncthreads();

    auto step = [&](int it, uint2 (&bc)[8], uint2 (&bn)[8]) {
        const int cur = it & 1;
        // prefetch next chunk's B fragments (L2-resident gsplit, coalesced)
        const int cn = (it + 1 < NCHUNK) ? it + 1 : NCHUNK - 1;
#pragma unroll
        for (int s = 0; s < 4; ++s) {
            const int k8g = cn * 8 + h * 4 + s;
            bn[2 * s + 0] = gs[((size_t)(k8g * 2 + 0) * 2 + ntp) * 64 + lane];
            bn[2 * s + 1] = gs[((size_t)(k8g * 2 + 1) * 2 + ntp) * 64 + lane];
        }
        // stage next chunk's A tile (split2 in regs -> 4 ds_write_b64)
        if (it + 1 < NCHUNK) stageA(cur ^ 1, ap0, ap1);
        // prefetch A for chunk it+2 (HBM nt, 2-chunk distance)
        const int ca = (it + 2 < NCHUNK) ? it + 2 : NCHUNK - 1;
        ap0 = __builtin_nontemporal_load(&A4[abase + (size_t)ca * 16]);
        ap1 = __builtin_nontemporal_load(&A4[abase + (size_t)ca * 16 + 1]);
        // compute: 4 k8-steps x (2 ds_read_b64 + 4 MFMA)
#pragma unroll
        for (int s = 0; s < 4; ++s) {
            const int k8 = h * 4 + s;
            const int slot = lane ^ ((k8 & 1) << 3);
            bh4 a0 = __builtin_bit_cast(bh4, Af[cur][k8][0][slot]);
            bh4 a1 = __builtin_bit_cast(bh4, Af[cur][k8][1][slot]);
            bh4 b0 = __builtin_bit_cast(bh4, bc[2 * s + 0]);
            bh4 b1 = __builtin_bit_cast(bh4, bc[2 * s + 1]);
            acc = mfma_bf16(a0, b0, acc);
            acc = mfma_bf16(a1, b0, acc);
            acc = mfma_bf16(a0, b1, acc);
            acc = mfma_bf16(a1, b1, acc);
        }
        barrier_lgkm_only();
    };

    for (int it = 0; it < NCHUNK; it += 2) {
        step(it, bA, bB);
        step(it + 1, bB, bA);
    }

    // MFMA -> VALU/LDS hazard guard
    asm volatile("s_nop 7\n\ts_nop 7" :::);

    if (h == 1) {
#pragma unroll
        for (int r = 0; r < 16; ++r) Pacc[ntp][r][lane] = acc[r];
    }
    if (t < NEXP) hist[t] = 0u;
    __syncthreads();
    if (h == 0) {
        // D layout [R6-verified]: col=lane&31, row=(r&3)+8*(r>>2)+4*(lane>>5)
#pragma unroll
        for (int r = 0; r < 16; ++r) {
            float x = acc[r] + Pacc[ntp][r][lane];
            const int tok = (r & 3) + 8 * (r >> 2) + 4 * (lane >> 5);
            const int e = ntp * 32 + (lane & 31);
            C_lds[tok * CSTRIDE + e] = x;
        }
    }
    __syncthreads();

    if (wave != 0) return;   // epilogue on wave 0 (lanes 0..31 = tokens)

    float z = 0.f;
    if (lane < MBLK) {
        // top-2 (strict >, ascending e => ties pick lower index, matches jax)
        float v1 = -INFINITY, v2 = -INFINITY;
        int i1 = 0, i2 = 0;
        for (int e = 0; e < NEXP; ++e) {
            float v = C_lds[lane * CSTRIDE + e];
            if (v > v1)      { v2 = v1; i2 = i1; v1 = v; i1 = e; }
            else if (v > v2) { v2 = v;  i2 = e; }
        }
        atomicAdd(&hist[i1], 1u);
        atomicAdd(&hist[i2], 1u);

        float d = 0.f;
        for (int e = 0; e < NEXP; ++e) {
            float ev = expf(C_lds[lane * CSTRIDE + e] - v1);
            C_lds[lane * CSTRIDE + e] = ev;
            d += ev;
        }
        rden[lane] = 1.0f / d;
        float lse = v1 + logf(d);
        z = lse * lse;

        float e2 = expf(v2 - v1);
        float w2 = e2 / (1.f + e2);
        float w1 = 1.f - w2;
        int tok = m0 + lane;
        out_rw[2 * tok + 0] = w1;
        out_rw[2 * tok + 1] = w2;
        out_sel[2 * tok + 0] = (float)i1;
        out_sel[2 * tok + 1] = (float)i2;
    }

#pragma unroll
    for (int off = 32; off > 0; off >>= 1) z += __shfl_down(z, off);
    if (lane == 0) atomicAdd(zsum_g, z);

    // per-expert prob sums over this block's 32 tokens (lane = expert)
    float ps = 0.f;
    for (int m = 0; m < MBLK; ++m)
        ps += C_lds[m * CSTRIDE + lane] * rden[m];
    atomicAdd(&psum_g[lane], ps);
    atomicAdd(&cnt_g[lane], (float)hist[lane]);
}

__global__ void router_final(const float* __restrict__ ws, float* __restrict__ out_loss)
{
    int e = threadIdx.x;  // 64 threads
    const float inv = 1.0f / (float)NTOK;
    float p = (ws[64 + e] * inv) * (ws[e] * inv);
#pragma unroll
    for (int off = 32; off > 0; off >>= 1) p += __shfl_down(p, off);
    if (e == 0)
        out_loss[0] = 0.01f * (64.f * p) + 0.001f * (ws[128] * inv);
}

extern "C" void kernel_launch(void* const* d_in, const int* in_sizes, int n_in,
                              void* d_out, int out_size, void* d_ws, size_t ws_size,
                              hipStream_t stream) {
    const float* hidden = (const float*)d_in[0];   // [4,4096,4096] fp32
    const float* gate   = (const float*)d_in[1];   // [64,4096] fp32
    float* out = (float*)d_out;                    // 65537 floats
    float* ws  = (float*)d_ws;                     // gsplit 1MB | psum[64] cnt[64] zsum[1]
    float* stats = ws + GS_FLOATS;

    hipMemsetAsync(stats, 0, 129 * sizeof(float), stream);
    gate_presplit<<<dim3(256), dim3(256), 0, stream>>>(gate, (uint2*)ws);
    router_main<<<dim3(NTOK / MBLK), dim3(256), 0, stream>>>(
        hidden, (const uint2*)ws,
        out,                 // routing weights
        out + NTOK * 2,      // selected experts (as floats)
        stats, stats + 64, stats + 128);
    router_final<<<dim3(1), dim3(64), 0, stream>>>(stats, out + NTOK * 4);
}